// Round 9
// baseline (800.958 us; speedup 1.0000x reference)
//
#include <hip/hip_runtime.h>
#include <hip/hip_bf16.h>
#include <math.h>

#define HH 80
#define WW 80
#define NPIX 6400
#define LL 21
#define NITER 5
#define C_LOG2E 1.44269504088896f

// bilateral MFMA kernel geometry
#define SJ  320             // j-slice per block
#define CHK (SJ / 32)       // 10 chunks of 32 j
#define QROW 164            // Q LDS row stride in u32 (320 bf16 + pad, 656 B)
#define NBILAT 1000         // 50 x 20 bilat blocks; == co-residency capacity (4/CU)
#define NSPAT  525          // 21 planes x 25 pixel-tiles, ride on blocks 0..524
#define NBY    20           // j0 slices (partial-accumulator count)

typedef short short8 __attribute__((ext_vector_type(8)));
typedef float f32x16 __attribute__((ext_vector_type(16)));

__device__ inline ushort bf_rne(float x) {
    uint u = __float_as_uint(x);
    return (ushort)((u + 0x7FFFu + ((u >> 16) & 1u)) >> 16);
}
__device__ inline float bf_to_f(ushort h) { return __uint_as_float(((uint)h) << 16); }
__device__ inline uint pk2(float a, float b) {
    __hip_bfloat162 t = __float22bfloat162_rn(make_float2(a, b));
    return *reinterpret_cast<uint*>(&t);
}
__device__ inline float fexp2(float x) { return __builtin_amdgcn_exp2f(x); }

// ================ setup: blocks 0..24 = pre+softmax0, block 25 = mats
__global__ void k_setup(const float* __restrict__ img, const float* __restrict__ unary,
                        const float* __restrict__ Wsp, const float* __restrict__ Wbi,
                        const float* __restrict__ C, ushort* __restrict__ fjg,
                        uint* __restrict__ fig, float* __restrict__ mhs,
                        float* __restrict__ nsp, float* __restrict__ q,
                        ushort* __restrict__ qb16, float* __restrict__ M1,
                        float* __restrict__ M2) {
    int tid = threadIdx.x;
    if (blockIdx.x == 25) {           // ---- mats role
        for (int t = tid; t < LL * LL; t += 256) {
            int l = t / LL, k = t % LL;
            float a = 0.f, b = 0.f;
            for (int m = 0; m < LL; m++) {
                a += C[l * LL + m] * Wsp[m * LL + k];
                b += C[l * LL + m] * Wbi[m * LL + k];
            }
            M1[t] = a; M2[t] = b;
        }
        return;
    }
    __shared__ float sxT[WW];
    if (tid < WW) {
        float s = 0.f;
        for (int t = 0; t < WW; t++) { float d = (float)(tid - t); s += __expf(-d * d * (1.0f / 18.0f)); }
        sxT[tid] = s;
    }
    __syncthreads();
    int i = blockIdx.x * 256 + tid;
    int x = i % WW, y = i / WW;
    float f[5];
    f[0] = (float)x * (1.0f / 160.0f);
    f[1] = (float)y * (1.0f / 160.0f);
    f[2] = (img[0 * NPIX + i] - 127.5f) * (1.0f / 3.0f);
    f[3] = (img[1 * NPIX + i] - 127.5f) * (1.0f / 3.0f);
    f[4] = (img[2 * NPIX + i] - 127.5f) * (1.0f / 3.0f);
    float s = 0.f;
    ushort hi[5], lo[5], Hi[5], Lo[5];
#pragma unroll
    for (int c = 0; c < 5; c++) {
        s += f[c] * f[c];
        hi[c] = bf_rne(f[c]);
        lo[c] = bf_rne(f[c] - bf_to_f(hi[c]));
        float a = C_LOG2E * f[c];
        Hi[c] = bf_rne(a);
        Lo[c] = bf_rne(a - bf_to_f(Hi[c]));
    }
    float mi = -0.5f * C_LOG2E * s;
    mhs[i] = mi;
    ushort mih = bf_rne(mi);
    ushort mil = bf_rne(mi - bf_to_f(mih));
    {   // A-side row: [h0..h4, l2,l3,l4, h2,h3,h4, l2,l3,l4, 1.0, 1.0]
        ushort r0[16] = { hi[0], hi[1], hi[2], hi[3], hi[4], lo[2], lo[3], lo[4],
                          hi[2], hi[3], hi[4], lo[2], lo[3], lo[4], 0x3F80, 0x3F80 };
        uint4 w0, w1;
        w0.x = (uint)r0[0] | ((uint)r0[1] << 16);  w0.y = (uint)r0[2] | ((uint)r0[3] << 16);
        w0.z = (uint)r0[4] | ((uint)r0[5] << 16);  w0.w = (uint)r0[6] | ((uint)r0[7] << 16);
        w1.x = (uint)r0[8] | ((uint)r0[9] << 16);  w1.y = (uint)r0[10] | ((uint)r0[11] << 16);
        w1.z = (uint)r0[12] | ((uint)r0[13] << 16); w1.w = (uint)r0[14] | ((uint)r0[15] << 16);
        *(uint4*)(fjg + (size_t)i * 16) = w0;
        *(uint4*)(fjg + (size_t)i * 16 + 8) = w1;
    }
    {   // B-side row: [H0..H4, H2,H3,H4, L2,L3,L4, L2,L3,L4, mih, mil]
        ushort r1[16] = { Hi[0], Hi[1], Hi[2], Hi[3], Hi[4], Hi[2], Hi[3], Hi[4],
                          Lo[2], Lo[3], Lo[4], Lo[2], Lo[3], Lo[4], mih, mil };
        uint4 w0, w1;
        w0.x = (uint)r1[0] | ((uint)r1[1] << 16);  w0.y = (uint)r1[2] | ((uint)r1[3] << 16);
        w0.z = (uint)r1[4] | ((uint)r1[5] << 16);  w0.w = (uint)r1[6] | ((uint)r1[7] << 16);
        w1.x = (uint)r1[8] | ((uint)r1[9] << 16);  w1.y = (uint)r1[10] | ((uint)r1[11] << 16);
        w1.z = (uint)r1[12] | ((uint)r1[13] << 16); w1.w = (uint)r1[14] | ((uint)r1[15] << 16);
        *(uint4*)(fig + (size_t)i * 8) = w0;
        *(uint4*)(fig + (size_t)i * 8 + 4) = w1;
    }
    nsp[i] = 1.0f / (sxT[x] * sxT[y] + 1e-8f);
    float v[LL];
    float mx = -1e30f;
    for (int l = 0; l < LL; l++) { v[l] = unary[l * NPIX + i]; mx = fmaxf(mx, v[l]); }
    float ss = 0.f;
    for (int l = 0; l < LL; l++) { v[l] = __expf(v[l] - mx); ss += v[l]; }
    float r = 1.0f / ss;
    for (int l = 0; l < LL; l++) {
        float qv = v[l] * r;
        q[l * NPIX + i] = qv;
        qb16[(size_t)l * NPIX + i] = bf_rne(qv);
    }
}

__device__ inline f32x16 ldmhs(const float* p, int h) {
    float4 a0 = *(const float4*)(p + 8 * h);
    float4 a1 = *(const float4*)(p + 8 * h + 4);
    float4 a2 = *(const float4*)(p + 16 + 8 * h);
    float4 a3 = *(const float4*)(p + 16 + 8 * h + 4);
    f32x16 cv;
    cv[0] = a0.x;  cv[1] = a0.y;  cv[2] = a0.z;  cv[3] = a0.w;
    cv[4] = a1.x;  cv[5] = a1.y;  cv[6] = a1.z;  cv[7] = a1.w;
    cv[8] = a2.x;  cv[9] = a2.y;  cv[10] = a2.z; cv[11] = a2.w;
    cv[12] = a3.x; cv[13] = a3.y; cv[14] = a3.z; cv[15] = a3.w;
    return cv;
}

// ================ iteration kernel 1: 1000 blocks, all co-resident.
// All blocks: bilat tile (bx=bid%50 -> 128 i, by=bid/50 -> 320 j).
// Blocks 0..524 additionally run one spat_x unit afterwards.
__global__ __launch_bounds__(256, 4)
void k_iter1(const float* __restrict__ mhs, const ushort* __restrict__ fjg,
             const uint* __restrict__ fig, const float* __restrict__ q,
             const ushort* __restrict__ qb16, float* __restrict__ bip,
             float* __restrict__ tmpx) {
    __shared__ __align__(16) uint  FjL[SJ * 12];
    __shared__ __align__(16) float mhsL[SJ];
    __shared__ __align__(16) uint  QL[32 * QROW];
    __shared__ float gT[WW];
    int tid = threadIdx.x;
    int bid = blockIdx.x;
    int bx = bid % 50, by = bid / 50;
    int j0 = by * SJ;
    // ---- stage Fj rows (32 B each -> 48-B LDS rows)
    for (int idx = tid; idx < SJ * 2; idx += 256) {
        int r = idx >> 1, hf = idx & 1;
        uint4 v = ((const uint4*)(fjg + (size_t)(j0 + r) * 16))[hf];
        *(uint4*)&FjL[r * 12 + hf * 4] = v;
    }
    for (int idx = tid; idx < SJ; idx += 256) mhsL[idx] = mhs[j0 + idx];
    if (tid < WW) gT[tid] = __expf(-(float)(tid * tid) * (1.0f / 18.0f));
    // ---- stage Q (bf16 in global) as [32 l-rows][SJ j]
    {
        int l = tid >> 3;             // 0..31, 8 threads per row
        int t0 = tid & 7;
#pragma unroll
        for (int t = 0; t < 20; t++) {
            int jp = t0 + (t << 3);
            uint v;
            if (l < LL) {
                const uint* p = (const uint*)qb16 + (((size_t)l * NPIX + j0) >> 1);
                v = p[jp];
            } else if (l == LL) {
                v = 0x3F803F80u;
            } else {
                v = 0u;
            }
            QL[l * QROW + jp] = v;
        }
    }
    int lane = tid & 63, wid = tid >> 6;
    int h = lane >> 5, m = lane & 31;
    int i = bx * 128 + wid * 32 + m;
    union U8 { uint u[4]; short8 s; };
    U8 bfr;
    {
        uint4 bv = *(const uint4*)(fig + (size_t)i * 8 + h * 4);
        bfr.u[0] = bv.x; bfr.u[1] = bv.y; bfr.u[2] = bv.z; bfr.u[3] = bv.w;
    }
    // A-frag row permutation: swap bit2<->bit3 so D1 rows align with mfma2 B k-slots
    int jrow = (m & ~12) | ((m & 4) << 1) | ((m & 8) >> 1);
    __syncthreads();
    f32x16 acc;
#pragma unroll
    for (int k = 0; k < 16; k++) acc[k] = 0.f;
    const uint* qbase = &QL[m * QROW + h * 4];
    // prefetch chunk 0 fragments
    short8 af = *(const short8*)&FjL[jrow * 12 + h * 4];
    short8 qa = *(const short8*)qbase;
    short8 qb = *(const short8*)(qbase + 8);
    for (int c = 0; c < CHK; c++) {
        int jb = c * 32;
        f32x16 cv = ldmhs(&mhsL[jb], h);
        f32x16 d1 = __builtin_amdgcn_mfma_f32_32x32x16_bf16(af, bfr.s, cv, 0, 0, 0);
        // prefetch next chunk's fragments (clamped; covers ds_read latency)
        int cn = (c + 1 < CHK) ? c + 1 : c;
        short8 afn = *(const short8*)&FjL[(cn * 32 + jrow) * 12 + h * 4];
        short8 qan = *(const short8*)(qbase + cn * 16);
        short8 qbn = *(const short8*)(qbase + cn * 16 + 8);
        U8 ea;
        ea.u[0] = pk2(fexp2(d1[0]), fexp2(d1[1]));
        ea.u[1] = pk2(fexp2(d1[2]), fexp2(d1[3]));
        ea.u[2] = pk2(fexp2(d1[4]), fexp2(d1[5]));
        ea.u[3] = pk2(fexp2(d1[6]), fexp2(d1[7]));
        acc = __builtin_amdgcn_mfma_f32_32x32x16_bf16(qa, ea.s, acc, 0, 0, 0);
        U8 eb;
        eb.u[0] = pk2(fexp2(d1[8]),  fexp2(d1[9]));
        eb.u[1] = pk2(fexp2(d1[10]), fexp2(d1[11]));
        eb.u[2] = pk2(fexp2(d1[12]), fexp2(d1[13]));
        eb.u[3] = pk2(fexp2(d1[14]), fexp2(d1[15]));
        acc = __builtin_amdgcn_mfma_f32_32x32x16_bf16(qb, eb.s, acc, 0, 0, 0);
        af = afn; qa = qan; qb = qbn;
    }
#pragma unroll
    for (int r = 0; r < 16; r++) {
        int l = (r & 3) + 8 * (r >> 2) + 4 * h;
        if (l < LL + 1) bip[((size_t)by * (LL + 1) + l) * NPIX + i] = acc[r];
    }
    // ---- spat_x rider (gT written pre-barrier; barrier already passed)
    if (bid < NSPAT) {
        int l = bid / 25, pb = bid % 25;
        int p = pb * 256 + tid;
        int x = p % WW, y = p / WW;
        const float* rowq = q + (size_t)l * NPIX + y * WW;
        float s = 0.f;
        for (int xp = 0; xp < WW; xp++) {
            int d = x - xp; d = d < 0 ? -d : d;
            s += gT[d] * rowq[xp];
        }
        tmpx[(size_t)l * NPIX + p] = s;
    }
}

// ================ iteration kernel 2: spat_y + partial-reduce + combine + softmax
// 100 blocks x 256 thr: 64 px, 4 label-groups (wave-uniform lg).
// lg0..2: labels 0-4,5-9,10-14; lg3: 15-20 (+norm row 21 in the reduce).
__global__ void k_iter2(const float* __restrict__ unary, const float* __restrict__ tmpx,
                        const float* __restrict__ bip, const float* __restrict__ nsp,
                        const float* __restrict__ M1, const float* __restrict__ M2,
                        float* __restrict__ qout, ushort* __restrict__ qb16,
                        float* __restrict__ out, int last) {
    __shared__ float m1s[LL * 24];
    __shared__ float m2s[LL * 24];
    __shared__ float gT[HH];
    __shared__ float exS[64][25];
    __shared__ float exB[64][25];
    int tid = threadIdx.x;
    for (int t = tid; t < LL * LL; t += 256) {
        int l = t / LL, k = t % LL;
        m1s[l * 24 + k] = M1[t];
        m2s[l * 24 + k] = M2[t];
    }
    if (tid < HH) gT[tid] = __expf(-(float)(tid * tid) * (1.0f / 18.0f));
    __syncthreads();
    int pxl = tid & 63;
    int px = blockIdx.x * 64 + pxl;
    int lg = tid >> 6;
    int lb = lg * 5;
    int lc = (lg == 3) ? 6 : 5;       // spat/combine labels (l < 21)
    int rc = (lg == 3) ? 7 : 5;       // reduce rows (lg3 includes norm row 21)
    int x = px % WW, y = px / WW;
    // spat_y for own labels
    float sv[6];
#pragma unroll
    for (int u = 0; u < 6; u++) sv[u] = 0.f;
    for (int yp = 0; yp < HH; yp++) {
        int d = y - yp; d = d < 0 ? -d : d;
        float wv = gT[d];
        const float* base = tmpx + yp * WW + x;
        for (int u = 0; u < lc; u++)
            sv[u] = fmaf(wv, base[(size_t)(lb + u) * NPIX], sv[u]);
    }
    // bilat partial reduce for own rows
    float bv[7];
    for (int u = 0; u < rc; u++) {
        float s2 = 0.f;
        const float* p = bip + (size_t)(lb + u) * NPIX + px;
#pragma unroll
        for (int byi = 0; byi < NBY; byi++) s2 += p[(size_t)byi * (LL + 1) * NPIX];
        bv[u] = s2;
    }
    // exchange
    for (int u = 0; u < lc; u++) exS[pxl][lb + u] = sv[u];
    for (int u = 0; u < rc; u++) exB[pxl][lb + u] = bv[u];
    __syncthreads();
    float ns = nsp[px];
    float nb = 1.0f / (exB[pxl][LL] + 1e-8f);
    float a[6];
    for (int u = 0; u < lc; u++) {
        int l = lb + u;
        float s1 = 0.f, s2 = 0.f;
        const float* r1 = &m1s[l * 24];
        const float* r2 = &m2s[l * 24];
#pragma unroll
        for (int k = 0; k < LL; k++) {
            s1 = fmaf(r1[k], exS[pxl][k], s1);
            s2 = fmaf(r2[k], exB[pxl][k], s2);
        }
        a[u] = unary[l * NPIX + px] + ns * s1 + nb * s2;
    }
    if (last) {
        for (int u = 0; u < lc; u++) out[(size_t)(lb + u) * NPIX + px] = a[u];
        return;
    }
    __syncthreads();                  // all reads of exS done before overwrite
    for (int u = 0; u < lc; u++) exS[pxl][lb + u] = a[u];
    __syncthreads();
    float mx = -1e30f;
    for (int l = 0; l < LL; l++) mx = fmaxf(mx, exS[pxl][l]);
    float s = 0.f;
    for (int l = 0; l < LL; l++) s += __expf(exS[pxl][l] - mx);
    float r = 1.0f / s;
    for (int u = 0; u < lc; u++) {
        float qv = __expf(a[u] - mx) * r;
        qout[(size_t)(lb + u) * NPIX + px] = qv;
        qb16[(size_t)(lb + u) * NPIX + px] = bf_rne(qv);
    }
}

extern "C" void kernel_launch(void* const* d_in, const int* in_sizes, int n_in,
                              void* d_out, int out_size, void* d_ws, size_t ws_size,
                              hipStream_t stream) {
    const float* img   = (const float*)d_in[0];
    const float* unary = (const float*)d_in[1];
    const float* Wsp   = (const float*)d_in[2];
    const float* Wbi   = (const float*)d_in[3];
    const float* C     = (const float*)d_in[4];
    float* out = (float*)d_out;

    const int LN = LL * NPIX;
    float* w = (float*)d_ws;
    float*  q    = w;  w += LN;
    float*  tmpx = w;  w += LN;
    float*  bip  = w;  w += NBY * (LL + 1) * NPIX;    // per-j0-slice partials
    float*  mhs  = w;  w += NPIX;
    float*  nsp  = w;  w += NPIX;
    ushort* fjg  = (ushort*)w;  w += 8 * NPIX;        // A-rows [N][16 bf16]
    uint*   fig  = (uint*)w;    w += 8 * NPIX;        // B-rows [N][8 u32]
    ushort* qb16 = (ushort*)w;  w += (LN + 1) / 2;    // Q in bf16 [21][N]
    float*  M1   = w;  w += LL * LL;
    float*  M2   = w;  w += LL * LL;

    k_setup<<<26, 256, 0, stream>>>(img, unary, Wsp, Wbi, C, fjg, fig, mhs, nsp,
                                    q, qb16, M1, M2);
    for (int it = 0; it < NITER; it++) {
        int last = (it == NITER - 1);
        k_iter1<<<NBILAT, 256, 0, stream>>>(mhs, fjg, fig, q, qb16, bip, tmpx);
        k_iter2<<<NPIX / 64, 256, 0, stream>>>(unary, tmpx, bip, nsp, M1, M2, q, qb16,
                                               out, last);
    }
}

// Round 10
// 251.116 us; speedup vs baseline: 3.1896x; 3.1896x over previous
//
#include <hip/hip_runtime.h>
#include <hip/hip_bf16.h>
#include <math.h>

#define HH 80
#define WW 80
#define NPIX 6400
#define LL 21
#define NITER 5
#define C_LOG2E 1.44269504088896f

// bilateral MFMA kernel geometry
#define SJ  320             // j-slice per block
#define CHK (SJ / 32)       // 10 chunks of 32 j
#define QROW 164            // Q LDS row stride in u32 (320 bf16 + pad, 656 B)
#define NBILAT 1000         // 50 x 20 bilat blocks; == co-residency capacity (4/CU)
#define NSPAT  525          // 21 planes x 25 pixel-tiles, ride on blocks 0..524
#define NBY    20           // j0 slices (partial-accumulator count)

typedef short short8 __attribute__((ext_vector_type(8)));
typedef float f32x16 __attribute__((ext_vector_type(16)));

__device__ inline ushort bf_rne(float x) {
    uint u = __float_as_uint(x);
    return (ushort)((u + 0x7FFFu + ((u >> 16) & 1u)) >> 16);
}
__device__ inline float bf_to_f(ushort h) { return __uint_as_float(((uint)h) << 16); }
__device__ inline uint pk2(float a, float b) {
    __hip_bfloat162 t = __float22bfloat162_rn(make_float2(a, b));
    return *reinterpret_cast<uint*>(&t);
}
__device__ inline float fexp2(float x) { return __builtin_amdgcn_exp2f(x); }

// ================ setup: blocks 0..24 = pre+softmax0, block 25 = mats
__global__ void k_setup(const float* __restrict__ img, const float* __restrict__ unary,
                        const float* __restrict__ Wsp, const float* __restrict__ Wbi,
                        const float* __restrict__ C, ushort* __restrict__ fjg,
                        uint* __restrict__ fig, float* __restrict__ mhs,
                        float* __restrict__ nsp, float* __restrict__ q,
                        ushort* __restrict__ qb16, float* __restrict__ M1,
                        float* __restrict__ M2) {
    int tid = threadIdx.x;
    if (blockIdx.x == 25) {           // ---- mats role
        for (int t = tid; t < LL * LL; t += 256) {
            int l = t / LL, k = t % LL;
            float a = 0.f, b = 0.f;
            for (int m = 0; m < LL; m++) {
                a += C[l * LL + m] * Wsp[m * LL + k];
                b += C[l * LL + m] * Wbi[m * LL + k];
            }
            M1[t] = a; M2[t] = b;
        }
        return;
    }
    __shared__ float sxT[WW];
    if (tid < WW) {
        float s = 0.f;
        for (int t = 0; t < WW; t++) { float d = (float)(tid - t); s += __expf(-d * d * (1.0f / 18.0f)); }
        sxT[tid] = s;
    }
    __syncthreads();
    int i = blockIdx.x * 256 + tid;
    int x = i % WW, y = i / WW;
    float f[5];
    f[0] = (float)x * (1.0f / 160.0f);
    f[1] = (float)y * (1.0f / 160.0f);
    f[2] = (img[0 * NPIX + i] - 127.5f) * (1.0f / 3.0f);
    f[3] = (img[1 * NPIX + i] - 127.5f) * (1.0f / 3.0f);
    f[4] = (img[2 * NPIX + i] - 127.5f) * (1.0f / 3.0f);
    float s = 0.f;
    ushort hi[5], lo[5], Hi[5], Lo[5];
#pragma unroll
    for (int c = 0; c < 5; c++) {
        s += f[c] * f[c];
        hi[c] = bf_rne(f[c]);
        lo[c] = bf_rne(f[c] - bf_to_f(hi[c]));
        float a = C_LOG2E * f[c];
        Hi[c] = bf_rne(a);
        Lo[c] = bf_rne(a - bf_to_f(Hi[c]));
    }
    float mi = -0.5f * C_LOG2E * s;
    mhs[i] = mi;
    ushort mih = bf_rne(mi);
    ushort mil = bf_rne(mi - bf_to_f(mih));
    {   // A-side row: [h0..h4, l2,l3,l4, h2,h3,h4, l2,l3,l4, 1.0, 1.0]
        ushort r0[16] = { hi[0], hi[1], hi[2], hi[3], hi[4], lo[2], lo[3], lo[4],
                          hi[2], hi[3], hi[4], lo[2], lo[3], lo[4], 0x3F80, 0x3F80 };
        uint4 w0, w1;
        w0.x = (uint)r0[0] | ((uint)r0[1] << 16);  w0.y = (uint)r0[2] | ((uint)r0[3] << 16);
        w0.z = (uint)r0[4] | ((uint)r0[5] << 16);  w0.w = (uint)r0[6] | ((uint)r0[7] << 16);
        w1.x = (uint)r0[8] | ((uint)r0[9] << 16);  w1.y = (uint)r0[10] | ((uint)r0[11] << 16);
        w1.z = (uint)r0[12] | ((uint)r0[13] << 16); w1.w = (uint)r0[14] | ((uint)r0[15] << 16);
        *(uint4*)(fjg + (size_t)i * 16) = w0;
        *(uint4*)(fjg + (size_t)i * 16 + 8) = w1;
    }
    {   // B-side row: [H0..H4, H2,H3,H4, L2,L3,L4, L2,L3,L4, mih, mil]
        ushort r1[16] = { Hi[0], Hi[1], Hi[2], Hi[3], Hi[4], Hi[2], Hi[3], Hi[4],
                          Lo[2], Lo[3], Lo[4], Lo[2], Lo[3], Lo[4], mih, mil };
        uint4 w0, w1;
        w0.x = (uint)r1[0] | ((uint)r1[1] << 16);  w0.y = (uint)r1[2] | ((uint)r1[3] << 16);
        w0.z = (uint)r1[4] | ((uint)r1[5] << 16);  w0.w = (uint)r1[6] | ((uint)r1[7] << 16);
        w1.x = (uint)r1[8] | ((uint)r1[9] << 16);  w1.y = (uint)r1[10] | ((uint)r1[11] << 16);
        w1.z = (uint)r1[12] | ((uint)r1[13] << 16); w1.w = (uint)r1[14] | ((uint)r1[15] << 16);
        *(uint4*)(fig + (size_t)i * 8) = w0;
        *(uint4*)(fig + (size_t)i * 8 + 4) = w1;
    }
    nsp[i] = 1.0f / (sxT[x] * sxT[y] + 1e-8f);
    float v[LL];
    float mx = -1e30f;
    for (int l = 0; l < LL; l++) { v[l] = unary[l * NPIX + i]; mx = fmaxf(mx, v[l]); }
    float ss = 0.f;
    for (int l = 0; l < LL; l++) { v[l] = __expf(v[l] - mx); ss += v[l]; }
    float r = 1.0f / ss;
    for (int l = 0; l < LL; l++) {
        float qv = v[l] * r;
        q[l * NPIX + i] = qv;
        qb16[(size_t)l * NPIX + i] = bf_rne(qv);
    }
}

__device__ inline f32x16 ldmhs(const float* p, int h) {
    float4 a0 = *(const float4*)(p + 8 * h);
    float4 a1 = *(const float4*)(p + 8 * h + 4);
    float4 a2 = *(const float4*)(p + 16 + 8 * h);
    float4 a3 = *(const float4*)(p + 16 + 8 * h + 4);
    f32x16 cv;
    cv[0] = a0.x;  cv[1] = a0.y;  cv[2] = a0.z;  cv[3] = a0.w;
    cv[4] = a1.x;  cv[5] = a1.y;  cv[6] = a1.z;  cv[7] = a1.w;
    cv[8] = a2.x;  cv[9] = a2.y;  cv[10] = a2.z; cv[11] = a2.w;
    cv[12] = a3.x; cv[13] = a3.y; cv[14] = a3.z; cv[15] = a3.w;
    return cv;
}

// ================ iteration kernel 1: 1000 blocks, all co-resident.
// All blocks: bilat tile (bx=bid%50 -> 128 i, by=bid/50 -> 320 j).
// Blocks 0..524 additionally run one spat_x unit afterwards.
__global__ __launch_bounds__(256, 4)
void k_iter1(const float* __restrict__ mhs, const ushort* __restrict__ fjg,
             const uint* __restrict__ fig, const float* __restrict__ q,
             const ushort* __restrict__ qb16, float* __restrict__ bip,
             float* __restrict__ tmpx) {
    __shared__ __align__(16) uint  FjL[SJ * 12];
    __shared__ __align__(16) float mhsL[SJ];
    __shared__ __align__(16) uint  QL[32 * QROW];
    __shared__ float gT[WW];
    int tid = threadIdx.x;
    int bid = blockIdx.x;
    int bx = bid % 50, by = bid / 50;
    int j0 = by * SJ;
    // ---- stage Fj rows (32 B each -> 48-B LDS rows)
    for (int idx = tid; idx < SJ * 2; idx += 256) {
        int r = idx >> 1, hf = idx & 1;
        uint4 v = ((const uint4*)(fjg + (size_t)(j0 + r) * 16))[hf];
        *(uint4*)&FjL[r * 12 + hf * 4] = v;
    }
    for (int idx = tid; idx < SJ; idx += 256) mhsL[idx] = mhs[j0 + idx];
    if (tid < WW) gT[tid] = __expf(-(float)(tid * tid) * (1.0f / 18.0f));
    // ---- stage Q (bf16 in global) as [32 l-rows][SJ j]
    {
        int l = tid >> 3;             // 0..31, 8 threads per row
        int t0 = tid & 7;
#pragma unroll
        for (int t = 0; t < 20; t++) {
            int jp = t0 + (t << 3);
            uint v;
            if (l < LL) {
                const uint* p = (const uint*)qb16 + (((size_t)l * NPIX + j0) >> 1);
                v = p[jp];
            } else if (l == LL) {
                v = 0x3F803F80u;
            } else {
                v = 0u;
            }
            QL[l * QROW + jp] = v;
        }
    }
    int lane = tid & 63, wid = tid >> 6;
    int h = lane >> 5, m = lane & 31;
    int i = bx * 128 + wid * 32 + m;
    union U8 { uint u[4]; short8 s; };
    U8 bfr;
    {
        uint4 bv = *(const uint4*)(fig + (size_t)i * 8 + h * 4);
        bfr.u[0] = bv.x; bfr.u[1] = bv.y; bfr.u[2] = bv.z; bfr.u[3] = bv.w;
    }
    // A-frag row permutation: swap bit2<->bit3 so D1 rows align with mfma2 B k-slots
    int jrow = (m & ~12) | ((m & 4) << 1) | ((m & 8) >> 1);
    __syncthreads();
    f32x16 acc;
#pragma unroll
    for (int k = 0; k < 16; k++) acc[k] = 0.f;
    const uint* qbase = &QL[m * QROW + h * 4];
    // prefetch chunk 0 fragments
    short8 af = *(const short8*)&FjL[jrow * 12 + h * 4];
    short8 qa = *(const short8*)qbase;
    short8 qb = *(const short8*)(qbase + 8);
    for (int c = 0; c < CHK; c++) {
        int jb = c * 32;
        f32x16 cv = ldmhs(&mhsL[jb], h);
        f32x16 d1 = __builtin_amdgcn_mfma_f32_32x32x16_bf16(af, bfr.s, cv, 0, 0, 0);
        // prefetch next chunk's fragments (clamped; covers ds_read latency)
        int cn = (c + 1 < CHK) ? c + 1 : c;
        short8 afn = *(const short8*)&FjL[(cn * 32 + jrow) * 12 + h * 4];
        short8 qan = *(const short8*)(qbase + cn * 16);
        short8 qbn = *(const short8*)(qbase + cn * 16 + 8);
        U8 ea;
        ea.u[0] = pk2(fexp2(d1[0]), fexp2(d1[1]));
        ea.u[1] = pk2(fexp2(d1[2]), fexp2(d1[3]));
        ea.u[2] = pk2(fexp2(d1[4]), fexp2(d1[5]));
        ea.u[3] = pk2(fexp2(d1[6]), fexp2(d1[7]));
        acc = __builtin_amdgcn_mfma_f32_32x32x16_bf16(qa, ea.s, acc, 0, 0, 0);
        U8 eb;
        eb.u[0] = pk2(fexp2(d1[8]),  fexp2(d1[9]));
        eb.u[1] = pk2(fexp2(d1[10]), fexp2(d1[11]));
        eb.u[2] = pk2(fexp2(d1[12]), fexp2(d1[13]));
        eb.u[3] = pk2(fexp2(d1[14]), fexp2(d1[15]));
        acc = __builtin_amdgcn_mfma_f32_32x32x16_bf16(qb, eb.s, acc, 0, 0, 0);
        af = afn; qa = qan; qb = qbn;
    }
#pragma unroll
    for (int r = 0; r < 16; r++) {
        int l = (r & 3) + 8 * (r >> 2) + 4 * h;
        if (l < LL + 1) bip[((size_t)by * (LL + 1) + l) * NPIX + i] = acc[r];
    }
    // ---- spat_x rider (gT written pre-barrier; barrier already passed)
    if (bid < NSPAT) {
        int l = bid / 25, pb = bid % 25;
        int p = pb * 256 + tid;
        int x = p % WW, y = p / WW;
        const float* rowq = q + (size_t)l * NPIX + y * WW;
        float s = 0.f;
        for (int xp = 0; xp < WW; xp++) {
            int d = x - xp; d = d < 0 ? -d : d;
            s += gT[d] * rowq[xp];
        }
        tmpx[(size_t)l * NPIX + p] = s;
    }
}

// ================ iteration kernel 2: spat_y (l<21) + bilat partial reduce (all l)
// grid (20 ptiles, 22 l), 320 threads — 440 blocks (proven in R8)
__global__ void k_sy(const float* __restrict__ tmpx, const float* __restrict__ bip,
                     float* __restrict__ sp, float* __restrict__ bi) {
    __shared__ float gT[HH];
    int l = blockIdx.y, pt = blockIdx.x, tid = threadIdx.x;
    int px = pt * 320 + tid;
    if (l < LL) {
        if (tid < HH) gT[tid] = __expf(-(float)(tid * tid) * (1.0f / 18.0f));
        __syncthreads();
        int x = px % WW, y = px / WW;
        const float* base = tmpx + (size_t)l * NPIX + x;
        float s = 0.f;
        for (int yp = 0; yp < HH; yp++) {
            int d = y - yp; d = d < 0 ? -d : d;
            s += gT[d] * base[yp * WW];
        }
        sp[(size_t)l * NPIX + px] = s;
    }
    float s2 = 0.f;
#pragma unroll
    for (int by = 0; by < NBY; by++)
        s2 += bip[((size_t)by * (LL + 1) + l) * NPIX + px];
    bi[(size_t)l * NPIX + px] = s2;
}

// ================ iteration kernel 3: combine (+ fused softmax -> q, qb16)
__global__ void k_comb(const float* __restrict__ unary, const float* __restrict__ sp,
                       const float* __restrict__ bi, const float* __restrict__ nsp,
                       const float* __restrict__ M1, const float* __restrict__ M2,
                       float* __restrict__ qout, ushort* __restrict__ qb16,
                       float* __restrict__ out, int last) {
    __shared__ float m1s[LL * 24];
    __shared__ float m2s[LL * 24];
    int tid = threadIdx.x;
    for (int t = tid; t < LL * LL; t += 256) {
        int l = t / LL, k = t % LL;
        m1s[l * 24 + k] = M1[t];
        m2s[l * 24 + k] = M2[t];
    }
    __syncthreads();
    int i = blockIdx.x * 256 + tid;
    float ns = nsp[i];
    float nb = 1.0f / (bi[(size_t)LL * NPIX + i] + 1e-8f);
    float sv[LL], bv[LL];
#pragma unroll
    for (int k = 0; k < LL; k++) {
        sv[k] = sp[(size_t)k * NPIX + i] * ns;
        bv[k] = bi[(size_t)k * NPIX + i] * nb;
    }
    float a[LL];
    for (int l = 0; l < LL; l++) {
        float acc = unary[l * NPIX + i];
        const float* r1 = &m1s[l * 24];
        const float* r2 = &m2s[l * 24];
#pragma unroll
        for (int k = 0; k < LL; k++) acc += r1[k] * sv[k] + r2[k] * bv[k];
        a[l] = acc;
    }
    if (last) {
        for (int l = 0; l < LL; l++) out[l * NPIX + i] = a[l];
    } else {
        float mx = -1e30f;
        for (int l = 0; l < LL; l++) mx = fmaxf(mx, a[l]);
        float s = 0.f;
        for (int l = 0; l < LL; l++) { a[l] = __expf(a[l] - mx); s += a[l]; }
        float r = 1.0f / s;
        for (int l = 0; l < LL; l++) {
            float qv = a[l] * r;
            qout[l * NPIX + i] = qv;
            qb16[(size_t)l * NPIX + i] = bf_rne(qv);
        }
    }
}

extern "C" void kernel_launch(void* const* d_in, const int* in_sizes, int n_in,
                              void* d_out, int out_size, void* d_ws, size_t ws_size,
                              hipStream_t stream) {
    const float* img   = (const float*)d_in[0];
    const float* unary = (const float*)d_in[1];
    const float* Wsp   = (const float*)d_in[2];
    const float* Wbi   = (const float*)d_in[3];
    const float* C     = (const float*)d_in[4];
    float* out = (float*)d_out;

    const int LN = LL * NPIX;
    float* w = (float*)d_ws;
    float*  q    = w;  w += LN;
    float*  tmpx = w;  w += LN;
    float*  sp   = w;  w += LN;
    float*  bi   = w;  w += (LL + 1) * NPIX;          // reduced: 21 msg + 1 norm
    float*  bip  = w;  w += NBY * (LL + 1) * NPIX;    // per-j0-slice partials
    float*  mhs  = w;  w += NPIX;
    float*  nsp  = w;  w += NPIX;
    ushort* fjg  = (ushort*)w;  w += 8 * NPIX;        // A-rows [N][16 bf16]
    uint*   fig  = (uint*)w;    w += 8 * NPIX;        // B-rows [N][8 u32]
    ushort* qb16 = (ushort*)w;  w += (LN + 1) / 2;    // Q in bf16 [21][N]
    float*  M1   = w;  w += LL * LL;
    float*  M2   = w;  w += LL * LL;

    k_setup<<<26, 256, 0, stream>>>(img, unary, Wsp, Wbi, C, fjg, fig, mhs, nsp,
                                    q, qb16, M1, M2);
    for (int it = 0; it < NITER; it++) {
        int last = (it == NITER - 1);
        k_iter1<<<NBILAT, 256, 0, stream>>>(mhs, fjg, fig, q, qb16, bip, tmpx);
        k_sy<<<dim3(NBY, LL + 1), 320, 0, stream>>>(tmpx, bip, sp, bi);
        k_comb<<<NPIX / 256, 256, 0, stream>>>(unary, sp, bi, nsp, M1, M2, q, qb16,
                                               out, last);
    }
}